// Round 3
// baseline (163.914 us; speedup 1.0000x reference)
//
#include <hip/hip_runtime.h>
#include <hip/hip_bf16.h>

#define NEG 0.2f

// P layout (floats)
#define P_U   0      // 256 : u = W1 @ Wf
#define P_W   256    // 4*256 : w_t = W1 @ c_t + b1   [t*256 + hc]
#define P_PS  1280   // 4  : per-head src scale
#define P_PD  1284   // 4
#define P_QS  1288   // 16 : [t*4+h]
#define P_QD  1304   // 16
#define P_TW  1320   // 4  : softmax(temporal_attention)
#define P_WT  1324   // 1024 : wT[c*4+t] = P_W[t*256+c]  (float4-aligned: 1324%4==0)
#define P_CNT 2560

typedef __bf16 bf16x8 __attribute__((ext_vector_type(8)));
typedef float  f32x4  __attribute__((ext_vector_type(4)));

__device__ __forceinline__ float lrelu(float v){ return v > 0.f ? v : NEG*v; }
__device__ __forceinline__ unsigned short f2bf(float f){
    unsigned u = __float_as_uint(f);
    unsigned r = u + 0x7fffu + ((u >> 16) & 1u);
    return (unsigned short)(r >> 16);
}

// ---------------- Phase A: tiny precompute (1 block, 256 thr) ----------------
__global__ void precomputeK(const float* time_idx, const float* Wt, const float* bt,
                            const float* Wf, const float* bf, const float* W1,
                            const float* as1, const float* ad1, const float* b1,
                            const float* ta, const float* W2,
                            float* P, unsigned short* W2bf)
{
    int tid = threadIdx.x; // 0..255 (= hc)
    const float* wrow = W1 + tid*64;
    float uu = 0.f;
    for (int k = 0; k < 64; ++k) uu += wrow[k] * Wf[k];
    P[P_U + tid] = uu;
    for (int t = 0; t < 4; ++t){
        float ti = time_idx[t];
        float vv = 0.f;
        for (int k = 0; k < 64; ++k) vv += wrow[k] * (bf[k] + ti*Wt[k] + bt[k]);
        P[P_W + t*256 + tid] = vv + b1[tid];   // w_t (bias folded)
    }
    __syncthreads();
    if (tid < 4){ // per-head p
        int h = tid; float ps=0.f, pd=0.f;
        for (int c = 0; c < 64; ++c){
            float uv = P[P_U + h*64 + c];
            ps += uv * as1[h*64+c];
            pd += uv * ad1[h*64+c];
        }
        P[P_PS+h]=ps; P[P_PD+h]=pd;
    }
    if (tid < 16){ // q[t][h] from v = w - b1
        int t = tid >> 2, h = tid & 3;
        float qs=0.f, qd=0.f;
        for (int c = 0; c < 64; ++c){
            float v = P[P_W + t*256 + h*64 + c] - b1[h*64+c];
            qs += v * as1[h*64+c];
            qd += v * ad1[h*64+c];
        }
        P[P_QS + t*4 + h] = qs;
        P[P_QD + t*4 + h] = qd;
    }
    if (tid == 0){ // temporal softmax
        float m = ta[0];
        for (int t = 1; t < 4; ++t) m = fmaxf(m, ta[t]);
        float s = 0.f, e[4];
        for (int t = 0; t < 4; ++t){ e[t] = __expf(ta[t]-m); s += e[t]; }
        for (int t = 0; t < 4; ++t) P[P_TW+t] = e[t]/s;
    }
    // transposed w table for h2K phase-1 (needs P_W complete -> after barrier)
    for (int idx = tid; idx < 1024; idx += 256){
        int c = idx >> 2, t = idx & 3;
        P[P_WT + idx] = P[P_W + t*256 + c];
    }
    // W2 in bf16, plain row-major [out][k]
    for (int idx = tid; idx < 16384; idx += 256)
        W2bf[idx] = f2bf(W2[idx]);
}

// ---------------- CSR build ----------------
__global__ void zeroK(int* p, int n){
    int i = blockIdx.x*256 + threadIdx.x;
    if (i < n) p[i] = 0;
}
__global__ void countK(const int* ei, int E, int* deg){
    int e = blockIdx.x*256 + threadIdx.x;
    if (e < E) atomicAdd(&deg[ei[E+e]], 1);
}
__global__ void scanK(const int* deg, int* rowptr, int N){
    __shared__ int part[1024];
    int tid = threadIdx.x;
    int CH = (N + 1023) >> 10;
    int base = tid * CH;
    int sum = 0;
    for (int k = 0; k < CH; ++k){ int i = base+k; if (i < N) sum += deg[i]; }
    part[tid] = sum; __syncthreads();
    for (int off = 1; off < 1024; off <<= 1){
        int v = (tid >= off) ? part[tid-off] : 0;
        __syncthreads();
        part[tid] += v;
        __syncthreads();
    }
    int run = part[tid] - sum;  // exclusive
    for (int k = 0; k < CH; ++k){
        int i = base+k;
        if (i < N){ rowptr[i] = run; run += deg[i]; }
    }
    if (tid == 1023) rowptr[N] = part[1023];
}
__global__ void fillK(const int* ei, int E, const int* rowptr, int* cursor, int* csr){
    int e = blockIdx.x*256 + threadIdx.x;
    if (e >= E) return;
    int d = ei[E+e];
    int pos = rowptr[d] + atomicAdd(&cursor[d], 1);
    csr[pos] = ei[e];
}

// ---------------- GAT-1: thread per (node, t); exact max via monotonicity ----------------
__global__ void gat1K(const float* x, const int* rowptr, const int* csr,
                      const float* P, float* S, int N)
{
    int idx = blockIdx.x*256 + threadIdx.x;
    if (idx >= N*4) return;
    int n = idx >> 2, t = idx & 3;
    float xn = x[n*4 + t];
    float ps[4], qsum[4];
    #pragma unroll
    for (int h = 0; h < 4; ++h){
        float ad = xn*P[P_PD+h] + P[P_QD+t*4+h];
        ps[h] = P[P_PS+h];
        qsum[h] = P[P_QS+t*4+h] + ad;
    }
    int beg = rowptr[n], end = rowptr[n+1];
    // pass 1: min/max of x[s,t] (lrelu+affine are monotone -> exact segment max)
    float xmn = xn, xmx = xn;
    int j = beg;
    for (; j + 4 <= end; j += 4){
        float v0 = x[csr[j]*4 + t];
        float v1 = x[csr[j+1]*4 + t];
        float v2 = x[csr[j+2]*4 + t];
        float v3 = x[csr[j+3]*4 + t];
        xmn = fminf(fminf(xmn, v0), fminf(v1, v2));
        xmx = fmaxf(fmaxf(xmx, v0), fmaxf(v1, v2));
        xmn = fminf(xmn, v3); xmx = fmaxf(xmx, v3);
    }
    for (; j < end; ++j){
        float v = x[csr[j]*4 + t];
        xmn = fminf(xmn, v); xmx = fmaxf(xmx, v);
    }
    float m[4], den[4], num[4];
    #pragma unroll
    for (int h = 0; h < 4; ++h){
        float xe = ps[h] >= 0.f ? xmx : xmn;
        m[h] = lrelu(ps[h]*xe + qsum[h]);
        float ex = __expf(lrelu(xn*ps[h] + qsum[h]) - m[h]);   // self loop
        den[h] = ex; num[h] = ex*xn;
    }
    // pass 2: branch-free sums (x gathers L1-hot from pass 1)
    for (j = beg; j < end; ++j){
        float v = x[csr[j]*4 + t];
        #pragma unroll
        for (int h = 0; h < 4; ++h){
            float ex = __expf(lrelu(v*ps[h] + qsum[h]) - m[h]);
            den[h] += ex; num[h] += ex*v;
        }
    }
    #pragma unroll
    for (int h = 0; h < 4; ++h) S[n*16 + h*4 + t] = num[h]/den[h];
}

// ---------------- h2 = combined @ W2^T via MFMA (+ attention logit dots) ----------------
__launch_bounds__(256)
__global__ void h2K(const float* S, const float* P, const unsigned short* W2bfg,
                    const float* as2, const float* ad2,
                    float* h2, float* als2, float* ald2, int N)
{
    __shared__ unsigned short Abf[64*264];   // bf16 combined, row pad 264
    __shared__ float  Ul[256];
    __shared__ float4 WTl[256];
    __shared__ float  Twl[4];
    int tid = threadIdx.x;
    Ul[tid] = P[P_U + tid];
    WTl[tid] = reinterpret_cast<const float4*>(P + P_WT)[tid];
    if (tid < 4) Twl[tid] = P[P_TW + tid];
    __syncthreads();

    // phase 1: combined -> bf16 A tile
    int nl = tid >> 2, q = tid & 3;
    int gn = blockIdx.x*64 + nl;
    float tw0 = Twl[0], tw1 = Twl[1], tw2 = Twl[2], tw3 = Twl[3];
    unsigned int* arow = reinterpret_cast<unsigned int*>(&Abf[nl*264 + q*64]);
    if (gn < N){
        float4 s4 = reinterpret_cast<const float4*>(S)[gn*4 + q];
        #pragma unroll 8
        for (int j = 0; j < 64; j += 2){
            int c = q*64 + j;
            float4 wa = WTl[c];
            float4 wb = WTl[c+1];
            float ua = Ul[c], ub = Ul[c+1];
            float v0 = tw0*fmaxf(s4.x*ua + wa.x, 0.f)
                     + tw1*fmaxf(s4.y*ua + wa.y, 0.f)
                     + tw2*fmaxf(s4.z*ua + wa.z, 0.f)
                     + tw3*fmaxf(s4.w*ua + wa.w, 0.f);
            float v1 = tw0*fmaxf(s4.x*ub + wb.x, 0.f)
                     + tw1*fmaxf(s4.y*ub + wb.y, 0.f)
                     + tw2*fmaxf(s4.z*ub + wb.z, 0.f)
                     + tw3*fmaxf(s4.w*ub + wb.w, 0.f);
            arow[j>>1] = (unsigned)f2bf(v0) | ((unsigned)f2bf(v1) << 16);
        }
    } else {
        #pragma unroll
        for (int j = 0; j < 32; ++j) arow[j] = 0;
    }
    __syncthreads();

    // phase 2: MFMA 16x16x32, A from LDS, B (W2 bf16) from global
    int w = tid >> 6, lane = tid & 63, lr = lane & 15, lhi = lane >> 4;
    int r0 = w*16;
    bf16x8 a[8];
    #pragma unroll
    for (int kk = 0; kk < 8; ++kk)
        a[kk] = *reinterpret_cast<const bf16x8*>(&Abf[(r0+lr)*264 + kk*32 + lhi*8]);
    float s1[4] = {0.f,0.f,0.f,0.f}, s2[4] = {0.f,0.f,0.f,0.f};
    int gbase = blockIdx.x*64 + r0 + lhi*4;
    #pragma unroll
    for (int nt = 0; nt < 4; ++nt){
        f32x4 acc = {0.f,0.f,0.f,0.f};
        const unsigned short* bp = W2bfg + (nt*16 + lr)*256 + lhi*8;
        #pragma unroll
        for (int kk = 0; kk < 8; ++kk){
            bf16x8 b = *reinterpret_cast<const bf16x8*>(bp + kk*32);
            acc = __builtin_amdgcn_mfma_f32_16x16x32_bf16(a[kk], b, acc, 0, 0, 0);
        }
        float oas = as2[nt*16 + lr], oad = ad2[nt*16 + lr];
        #pragma unroll
        for (int r = 0; r < 4; ++r){
            int g = gbase + r;
            if (g < N) h2[g*64 + nt*16 + lr] = acc[r];
            s1[r] += acc[r]*oas;
            s2[r] += acc[r]*oad;
        }
    }
    #pragma unroll
    for (int r = 0; r < 4; ++r){
        float v1 = s1[r], v2 = s2[r];
        #pragma unroll
        for (int off = 8; off > 0; off >>= 1){
            v1 += __shfl_xor(v1, off);
            v2 += __shfl_xor(v2, off);
        }
        int g = gbase + r;
        if (lr == 0 && g < N){ als2[g] = v1; ald2[g] = v2; }
    }
}

// ---------------- GAT-2a: per-node exact max, per-edge weights, 1/den ----------------
__global__ void attnK(const float* als2, const float* ald2,
                      const int* rowptr, const int* csr,
                      float* aw, float* selfw, float* rden, int N)
{
    int n = blockIdx.x*256 + threadIdx.x;
    if (n >= N) return;
    float a_n = als2[n], aldn = ald2[n];
    int beg = rowptr[n], end = rowptr[n+1];
    float amax = a_n;
    int j = beg;
    for (; j + 4 <= end; j += 4){
        float v0 = als2[csr[j]];
        float v1 = als2[csr[j+1]];
        float v2 = als2[csr[j+2]];
        float v3 = als2[csr[j+3]];
        amax = fmaxf(fmaxf(amax, v0), fmaxf(v1, v2));
        amax = fmaxf(amax, v3);
    }
    for (; j < end; ++j) amax = fmaxf(amax, als2[csr[j]]);
    float m = lrelu(amax + aldn);     // lrelu monotone -> exact segment max
    float sw = __expf(lrelu(a_n + aldn) - m);
    float den = sw;
    for (j = beg; j < end; ++j){
        float ex = __expf(lrelu(als2[csr[j]] + aldn) - m);
        aw[j] = ex; den += ex;
    }
    selfw[n] = sw;
    rden[n] = 1.f/den;
}

// ---------------- GAT-2b: wave per node, pure gather-FMA PV ----------------
__global__ void pvK(const float* h2, const float* aw, const float* selfw,
                    const float* rden, const int* rowptr, const int* csr,
                    const float* b2, float* out, int N)
{
    int gw = (blockIdx.x*256 + threadIdx.x) >> 6;
    if (gw >= N) return;
    int n = gw, lane = threadIdx.x & 63;
    float acc = selfw[n] * h2[n*64 + lane];
    int beg = rowptr[n], end = rowptr[n+1];
    int j = beg;
    for (; j + 4 <= end; j += 4){
        int s0 = csr[j],   s1 = csr[j+1], s2 = csr[j+2], s3 = csr[j+3];
        float w0 = aw[j],  w1 = aw[j+1],  w2 = aw[j+2],  w3 = aw[j+3];
        float g0 = h2[s0*64 + lane];
        float g1 = h2[s1*64 + lane];
        float g2 = h2[s2*64 + lane];
        float g3 = h2[s3*64 + lane];
        acc += w0*g0; acc += w1*g1; acc += w2*g2; acc += w3*g3;
    }
    for (; j < end; ++j)
        acc += aw[j] * h2[csr[j]*64 + lane];
    out[n*64 + lane] = acc*rden[n] + b2[lane];
}

extern "C" void kernel_launch(void* const* d_in, const int* in_sizes, int n_in,
                              void* d_out, int out_size, void* d_ws, size_t ws_size,
                              hipStream_t stream)
{
    const float* x        = (const float*)d_in[0];
    const int*   ei       = (const int*)  d_in[1];
    const float* time_idx = (const float*)d_in[2];
    const float* Wt       = (const float*)d_in[3];
    const float* bt       = (const float*)d_in[4];
    const float* Wf       = (const float*)d_in[5];
    const float* bf       = (const float*)d_in[6];
    const float* W1       = (const float*)d_in[7];
    const float* as1      = (const float*)d_in[8];
    const float* ad1      = (const float*)d_in[9];
    const float* b1       = (const float*)d_in[10];
    const float* ta       = (const float*)d_in[11];
    const float* W2       = (const float*)d_in[12];
    const float* as2      = (const float*)d_in[13];
    const float* ad2      = (const float*)d_in[14];
    const float* b2       = (const float*)d_in[15];

    int N = in_sizes[0] / 4;   // x: [1,N,4]
    int E = in_sizes[1] / 2;   // edge_index: [2,E]

    char* w = (char*)d_ws;
    auto al = [](size_t v){ return (v + 255) & ~(size_t)255; };
    size_t off = 0;
    float* P     = (float*)(w + off); off = al(off + P_CNT*sizeof(float));
    unsigned short* W2bf = (unsigned short*)(w + off); off = al(off + 16384*sizeof(unsigned short));
    int*   deg   = (int*)  (w + off); off = al(off + (size_t)N*2*sizeof(int));
    int*   cursor = deg + N;
    int*   rowptr= (int*)  (w + off); off = al(off + ((size_t)N+1)*sizeof(int));
    int*   csr   = (int*)  (w + off); off = al(off + (size_t)E*sizeof(int));
    float* S     = (float*)(w + off); off = al(off + (size_t)N*16*sizeof(float));
    float* h2    = (float*)(w + off); off = al(off + (size_t)N*64*sizeof(float));
    float* als2  = (float*)(w + off); off = al(off + (size_t)N*sizeof(float));
    float* ald2  = (float*)(w + off); off = al(off + (size_t)N*sizeof(float));
    float* aw    = (float*)(w + off); off = al(off + (size_t)E*sizeof(float));
    float* selfw = (float*)(w + off); off = al(off + (size_t)N*sizeof(float));
    float* rden  = (float*)(w + off); off = al(off + (size_t)N*sizeof(float));
    (void)off; (void)ws_size; (void)n_in; (void)out_size;

    precomputeK<<<1, 256, 0, stream>>>(time_idx, Wt, bt, Wf, bf, W1, as1, ad1, b1, ta, W2, P, W2bf);
    zeroK<<<(2*N + 255)/256, 256, 0, stream>>>(deg, 2*N);
    countK<<<(E + 255)/256, 256, 0, stream>>>(ei, E, deg);
    scanK<<<1, 1024, 0, stream>>>(deg, rowptr, N);
    fillK<<<(E + 255)/256, 256, 0, stream>>>(ei, E, rowptr, cursor, csr);
    gat1K<<<(4*N + 255)/256, 256, 0, stream>>>(x, rowptr, csr, P, S, N);
    h2K<<<(N + 63)/64, 256, 0, stream>>>(S, P, W2bf, as2, ad2, h2, als2, ald2, N);
    attnK<<<(N + 255)/256, 256, 0, stream>>>(als2, ald2, rowptr, csr, aw, selfw, rden, N);
    pvK<<<((size_t)N*64 + 255)/256, 256, 0, stream>>>(h2, aw, selfw, rden, rowptr, csr, b2, (float*)d_out, N);
}

// Round 4
// 123.993 us; speedup vs baseline: 1.3220x; 1.3220x over previous
//
#include <hip/hip_runtime.h>
#include <hip/hip_bf16.h>

#define NEG 0.2f

// P layout (floats)
#define P_U   0      // 256 : u = W1 @ Wf
#define P_W   256    // 4*256 : w_t = W1 @ c_t + b1   [t*256 + hc]
#define P_PS  1280   // 4  : per-head src scale
#define P_PD  1284   // 4
#define P_QS  1288   // 16 : [t*4+h]
#define P_QD  1304   // 16
#define P_TW  1320   // 4  : softmax(temporal_attention)
#define P_WT  1324   // 1024 : wT[c*4+t] = P_W[t*256+c]
#define P_CNT 2560

typedef __bf16 bf16x8 __attribute__((ext_vector_type(8)));
typedef float  f32x4  __attribute__((ext_vector_type(4)));

__device__ __forceinline__ float lrelu(float v){ return v > 0.f ? v : NEG*v; }
__device__ __forceinline__ unsigned short f2bf(float f){
    unsigned u = __float_as_uint(f);
    unsigned r = u + 0x7fffu + ((u >> 16) & 1u);
    return (unsigned short)(r >> 16);
}

// ---------------- preK: block 0 = precompute; blocks 1.. = zero deg/cursor + W2->bf16 ----------------
__global__ void preK(const float* time_idx, const float* Wt, const float* bt,
                     const float* Wf, const float* bf, const float* W1,
                     const float* as1, const float* ad1, const float* b1,
                     const float* ta, const float* W2,
                     float* P, unsigned short* W2bf, int* deg2, int N)
{
    int tid = threadIdx.x;
    if (blockIdx.x != 0){
        int i0 = (blockIdx.x - 1)*256 + tid;
        int stride = (gridDim.x - 1)*256;
        for (int i = i0; i < 2*N; i += stride) deg2[i] = 0;
        for (int i = i0; i < 16384; i += stride) W2bf[i] = f2bf(W2[i]);
        return;
    }
    __shared__ float W1p[256][65];    // 65-pad: lane stride 65 -> conflict-free column reads
    for (int i = tid; i < 16384; i += 256){
        int r = i >> 6, c = i & 63;
        W1p[r][c] = W1[i];
    }
    __syncthreads();
    const float* wrow = W1p[tid];
    float uu = 0.f;
    for (int k = 0; k < 64; ++k) uu += wrow[k]*Wf[k];
    P[P_U + tid] = uu;
    for (int t = 0; t < 4; ++t){
        float ti = time_idx[t];
        float vv = 0.f;
        for (int k = 0; k < 64; ++k) vv += wrow[k]*(bf[k] + ti*Wt[k] + bt[k]);
        P[P_W + t*256 + tid] = vv + b1[tid];   // w_t (bias folded)
    }
    __syncthreads();
    if (tid < 4){ // per-head p
        int h = tid; float ps=0.f, pd=0.f;
        for (int c = 0; c < 64; ++c){
            float uv = P[P_U + h*64 + c];
            ps += uv * as1[h*64+c];
            pd += uv * ad1[h*64+c];
        }
        P[P_PS+h]=ps; P[P_PD+h]=pd;
    }
    if (tid < 16){ // q[t][h] from v = w - b1
        int t = tid >> 2, h = tid & 3;
        float qs=0.f, qd=0.f;
        for (int c = 0; c < 64; ++c){
            float v = P[P_W + t*256 + h*64 + c] - b1[h*64+c];
            qs += v * as1[h*64+c];
            qd += v * ad1[h*64+c];
        }
        P[P_QS + t*4 + h] = qs;
        P[P_QD + t*4 + h] = qd;
    }
    if (tid == 0){ // temporal softmax
        float m = ta[0];
        for (int t = 1; t < 4; ++t) m = fmaxf(m, ta[t]);
        float s = 0.f, e[4];
        for (int t = 0; t < 4; ++t){ e[t] = __expf(ta[t]-m); s += e[t]; }
        for (int t = 0; t < 4; ++t) P[P_TW+t] = e[t]/s;
    }
    __syncthreads();
    for (int idx = tid; idx < 1024; idx += 256){
        int c = idx >> 2, t = idx & 3;
        P[P_WT + idx] = P[P_W + t*256 + c];
    }
}

// ---------------- CSR build ----------------
__global__ void countK(const int* ei, int E, int* deg){
    int e = blockIdx.x*256 + threadIdx.x;
    if (e < E) atomicAdd(&deg[ei[E+e]], 1);
}
__global__ void scanK(const int* deg, int* rowptr, int N){
    __shared__ int part[1024];
    int tid = threadIdx.x;
    int CH = (N + 1023) >> 10;
    int base = tid * CH;
    int sum = 0;
    if ((CH & 3) == 0 && base + CH <= N){
        for (int k = 0; k < CH; k += 4){
            int4 v = *reinterpret_cast<const int4*>(deg + base + k);
            sum += v.x + v.y + v.z + v.w;
        }
    } else {
        for (int k = 0; k < CH; ++k){ int i = base+k; if (i < N) sum += deg[i]; }
    }
    part[tid] = sum; __syncthreads();
    for (int off = 1; off < 1024; off <<= 1){
        int v = (tid >= off) ? part[tid-off] : 0;
        __syncthreads();
        part[tid] += v;
        __syncthreads();
    }
    int run = part[tid] - sum;  // exclusive
    for (int k = 0; k < CH; ++k){
        int i = base+k;
        if (i < N){ rowptr[i] = run; run += deg[i]; }
    }
    if (tid == 1023) rowptr[N] = part[1023];
}
__global__ void fillK(const int* ei, int E, const int* rowptr, int* cursor, int* csr){
    int e = blockIdx.x*256 + threadIdx.x;
    if (e >= E) return;
    int d = ei[E+e];
    int pos = rowptr[d] + atomicAdd(&cursor[d], 1);
    csr[pos] = ei[e];
}

// ---------------- fused GAT-1 + combined + h2 MFMA (block owns 64 nodes) ----------------
__launch_bounds__(256)
__global__ void gat1h2K(const float* x, const int* rowptr, const int* csr,
                        const float* P, const unsigned short* W2bfg,
                        const float* as2, const float* ad2,
                        float* h2, float* als2, float* ald2, int N)
{
    __shared__ unsigned short Abf[64*264];   // bf16 combined, row pad 264
    __shared__ float4 Sl[64][4];             // S[node][head] over t
    __shared__ float  Ul[256];
    __shared__ float4 WTl[256];
    __shared__ float  Pl[44];                // PS(4) PD(4) QS(16) QD(16) TW(4)
    int tid = threadIdx.x;
    Ul[tid] = P[P_U + tid];
    WTl[tid] = reinterpret_cast<const float4*>(P + P_WT)[tid];
    if (tid < 44) Pl[tid] = P[P_PS + tid];
    __syncthreads();

    // phase 0: GAT-1 for 64 nodes; thread = (nl, t); exact max via lrelu monotonicity
    int nl = tid >> 2, t = tid & 3;
    int n  = blockIdx.x*64 + nl;
    {
        float s_out[4] = {0.f,0.f,0.f,0.f};
        if (n < N){
            float xn = x[n*4 + t];
            float ps[4], qsum[4];
            #pragma unroll
            for (int h = 0; h < 4; ++h){
                ps[h]   = Pl[h];
                qsum[h] = Pl[8 + t*4 + h] + xn*Pl[4 + h] + Pl[24 + t*4 + h];
            }
            int beg = rowptr[n], end = rowptr[n+1];
            float xmn = xn, xmx = xn;
            int j = beg;
            for (; j + 4 <= end; j += 4){
                float v0 = x[csr[j]*4 + t];
                float v1 = x[csr[j+1]*4 + t];
                float v2 = x[csr[j+2]*4 + t];
                float v3 = x[csr[j+3]*4 + t];
                xmn = fminf(fminf(xmn, v0), fminf(v1, v2));
                xmx = fmaxf(fmaxf(xmx, v0), fmaxf(v1, v2));
                xmn = fminf(xmn, v3); xmx = fmaxf(xmx, v3);
            }
            for (; j < end; ++j){
                float v = x[csr[j]*4 + t];
                xmn = fminf(xmn, v); xmx = fmaxf(xmx, v);
            }
            float m[4], den[4], num[4];
            #pragma unroll
            for (int h = 0; h < 4; ++h){
                float xe = ps[h] >= 0.f ? xmx : xmn;
                m[h] = lrelu(ps[h]*xe + qsum[h]);
                float ex = __expf(lrelu(xn*ps[h] + qsum[h]) - m[h]);   // self loop
                den[h] = ex; num[h] = ex*xn;
            }
            for (j = beg; j < end; ++j){
                float v = x[csr[j]*4 + t];
                #pragma unroll
                for (int h = 0; h < 4; ++h){
                    float ex = __expf(lrelu(v*ps[h] + qsum[h]) - m[h]);
                    den[h] += ex; num[h] += ex*v;
                }
            }
            #pragma unroll
            for (int h = 0; h < 4; ++h) s_out[h] = num[h]/den[h];
        }
        #pragma unroll
        for (int h = 0; h < 4; ++h)
            reinterpret_cast<float*>(&Sl[nl][h])[t] = s_out[h];
    }
    __syncthreads();

    // phase 1: combined -> bf16 A tile; thread = (nl, q=head)
    {
        float tw0 = Pl[40], tw1 = Pl[41], tw2 = Pl[42], tw3 = Pl[43];
        int q = t;
        float4 s4 = Sl[nl][q];
        unsigned int* arow = reinterpret_cast<unsigned int*>(&Abf[nl*264 + q*64]);
        #pragma unroll 8
        for (int jj = 0; jj < 64; jj += 2){
            int c = q*64 + jj;
            float4 wa = WTl[c], wb = WTl[c+1];
            float ua = Ul[c], ub = Ul[c+1];
            float v0 = tw0*fmaxf(s4.x*ua + wa.x, 0.f) + tw1*fmaxf(s4.y*ua + wa.y, 0.f)
                     + tw2*fmaxf(s4.z*ua + wa.z, 0.f) + tw3*fmaxf(s4.w*ua + wa.w, 0.f);
            float v1 = tw0*fmaxf(s4.x*ub + wb.x, 0.f) + tw1*fmaxf(s4.y*ub + wb.y, 0.f)
                     + tw2*fmaxf(s4.z*ub + wb.z, 0.f) + tw3*fmaxf(s4.w*ub + wb.w, 0.f);
            arow[jj>>1] = (unsigned)f2bf(v0) | ((unsigned)f2bf(v1) << 16);
        }
    }
    __syncthreads();

    // phase 2: MFMA 16x16x32, A from LDS, B (W2 bf16) from global
    int w = tid >> 6, lane = tid & 63, lr = lane & 15, lhi = lane >> 4;
    int r0 = w*16;
    bf16x8 a[8];
    #pragma unroll
    for (int kk = 0; kk < 8; ++kk)
        a[kk] = *reinterpret_cast<const bf16x8*>(&Abf[(r0+lr)*264 + kk*32 + lhi*8]);
    float s1[4] = {0.f,0.f,0.f,0.f}, s2[4] = {0.f,0.f,0.f,0.f};
    int gbase = blockIdx.x*64 + r0 + lhi*4;
    #pragma unroll
    for (int nt = 0; nt < 4; ++nt){
        f32x4 acc = {0.f,0.f,0.f,0.f};
        const unsigned short* bp = W2bfg + (nt*16 + lr)*256 + lhi*8;
        #pragma unroll
        for (int kk = 0; kk < 8; ++kk){
            bf16x8 b = *reinterpret_cast<const bf16x8*>(bp + kk*32);
            acc = __builtin_amdgcn_mfma_f32_16x16x32_bf16(a[kk], b, acc, 0, 0, 0);
        }
        float oas = as2[nt*16 + lr], oad = ad2[nt*16 + lr];
        #pragma unroll
        for (int r = 0; r < 4; ++r){
            int g = gbase + r;
            if (g < N) h2[g*64 + nt*16 + lr] = acc[r];
            s1[r] += acc[r]*oas;
            s2[r] += acc[r]*oad;
        }
    }
    #pragma unroll
    for (int r = 0; r < 4; ++r){
        float v1 = s1[r], v2 = s2[r];
        #pragma unroll
        for (int off = 8; off > 0; off >>= 1){
            v1 += __shfl_xor(v1, off);
            v2 += __shfl_xor(v2, off);
        }
        int g = gbase + r;
        if (lr == 0 && g < N){ als2[g] = v1; ald2[g] = v2; }
    }
}

// ---------------- fused GAT-2: wave per node; exact max, LDS-staged (s,w), gather PV ----------------
__launch_bounds__(256)
__global__ void attnpvK(const float* h2, const float* als2, const float* ald2,
                        const int* rowptr, const int* csr, const float* b2,
                        float* out, int N)
{
    __shared__ int   sbuf[4][64];
    __shared__ float wbuf[4][64];
    int wv = threadIdx.x >> 6, lane = threadIdx.x & 63;
    int n = blockIdx.x*4 + wv;
    if (n >= N) return;
    float aldn = ald2[n], a_n = als2[n];
    int beg = rowptr[n], end = rowptr[n+1];
    // pass A: exact segment max (lrelu monotone)
    float amax = a_n;
    for (int j = beg + lane; j < end; j += 64)
        amax = fmaxf(amax, als2[csr[j]]);
    #pragma unroll
    for (int off = 32; off; off >>= 1) amax = fmaxf(amax, __shfl_xor(amax, off));
    float m = lrelu(amax + aldn);
    float sw = __expf(lrelu(a_n + aldn) - m);
    float den = sw;
    float acc = sw * h2[n*64 + lane];
    // pass B: weights + PV
    for (int base = beg; base < end; base += 64){
        int j = base + lane;
        int cnt = min(64, end - base);
        int s = 0; float ex = 0.f;
        if (j < end){ s = csr[j]; ex = __expf(lrelu(als2[s] + aldn) - m); }
        sbuf[wv][lane] = s; wbuf[wv][lane] = ex;
        float sx = ex;
        #pragma unroll
        for (int off = 32; off; off >>= 1) sx += __shfl_xor(sx, off);
        den += sx;
        int i = 0;
        for (; i + 4 <= cnt; i += 4){
            int   s0 = sbuf[wv][i],   s1 = sbuf[wv][i+1], s2 = sbuf[wv][i+2], s3 = sbuf[wv][i+3];
            float w0 = wbuf[wv][i],   w1 = wbuf[wv][i+1], w2 = wbuf[wv][i+2], w3 = wbuf[wv][i+3];
            float g0 = h2[s0*64 + lane];
            float g1 = h2[s1*64 + lane];
            float g2 = h2[s2*64 + lane];
            float g3 = h2[s3*64 + lane];
            acc += w0*g0; acc += w1*g1; acc += w2*g2; acc += w3*g3;
        }
        for (; i < cnt; ++i)
            acc += wbuf[wv][i] * h2[sbuf[wv][i]*64 + lane];
    }
    out[n*64 + lane] = acc/den + b2[lane];
}

extern "C" void kernel_launch(void* const* d_in, const int* in_sizes, int n_in,
                              void* d_out, int out_size, void* d_ws, size_t ws_size,
                              hipStream_t stream)
{
    const float* x        = (const float*)d_in[0];
    const int*   ei       = (const int*)  d_in[1];
    const float* time_idx = (const float*)d_in[2];
    const float* Wt       = (const float*)d_in[3];
    const float* bt       = (const float*)d_in[4];
    const float* Wf       = (const float*)d_in[5];
    const float* bf       = (const float*)d_in[6];
    const float* W1       = (const float*)d_in[7];
    const float* as1      = (const float*)d_in[8];
    const float* ad1      = (const float*)d_in[9];
    const float* b1       = (const float*)d_in[10];
    const float* ta       = (const float*)d_in[11];
    const float* W2       = (const float*)d_in[12];
    const float* as2      = (const float*)d_in[13];
    const float* ad2      = (const float*)d_in[14];
    const float* b2       = (const float*)d_in[15];

    int N = in_sizes[0] / 4;   // x: [1,N,4]
    int E = in_sizes[1] / 2;   // edge_index: [2,E]

    char* w = (char*)d_ws;
    auto al = [](size_t v){ return (v + 255) & ~(size_t)255; };
    size_t off = 0;
    float* P     = (float*)(w + off); off = al(off + P_CNT*sizeof(float));
    unsigned short* W2bf = (unsigned short*)(w + off); off = al(off + 16384*sizeof(unsigned short));
    int*   deg   = (int*)  (w + off); off = al(off + (size_t)N*2*sizeof(int));
    int*   cursor = deg + N;
    int*   rowptr= (int*)  (w + off); off = al(off + ((size_t)N+1)*sizeof(int));
    int*   csr   = (int*)  (w + off); off = al(off + (size_t)E*sizeof(int));
    float* h2    = (float*)(w + off); off = al(off + (size_t)N*64*sizeof(float));
    float* als2  = (float*)(w + off); off = al(off + (size_t)N*sizeof(float));
    float* ald2  = (float*)(w + off); off = al(off + (size_t)N*sizeof(float));
    (void)off; (void)ws_size; (void)n_in; (void)out_size;

    preK<<<40, 256, 0, stream>>>(time_idx, Wt, bt, Wf, bf, W1, as1, ad1, b1, ta, W2, P, W2bf, deg, N);
    countK<<<(E + 255)/256, 256, 0, stream>>>(ei, E, deg);
    scanK<<<1, 1024, 0, stream>>>(deg, rowptr, N);
    fillK<<<(E + 255)/256, 256, 0, stream>>>(ei, E, rowptr, cursor, csr);
    gat1h2K<<<(N + 63)/64, 256, 0, stream>>>(x, rowptr, csr, P, W2bf, as2, ad2, h2, als2, ald2, N);
    attnpvK<<<(N + 3)/4, 256, 0, stream>>>(h2, als2, ald2, rowptr, csr, b2, (float*)d_out, N);
}